// Round 2
// baseline (825.864 us; speedup 1.0000x reference)
//
#include <hip/hip_runtime.h>
#include <hip/hip_bf16.h>

#define N_NODES 50000
#define N_EDGES 1600000
#define NREL    16
#define DIM     64

#define BKT_SH  5
#define BKT_SZ  32
#define NBKT    1563          // ceil(50000/32) buckets of 32 dst nodes
#define P1_CHUNK 2048
#define P1_GRID  782          // ceil(1.6M/2048)
#define SEG_PAD  256          // per-bucket slack: 16-align + 16 segs * <=15 pad
#define EMAX    (N_EDGES + NBKT * SEG_PAD)   // 2,000,128 edge slots
#define PREP_HBLK 3125        // 3.2M h elems / 1024 per block

typedef __attribute__((ext_vector_type(8))) short short8;
typedef __attribute__((ext_vector_type(4))) float float4v;
typedef __attribute__((ext_vector_type(4))) unsigned short ushort4v;

template<int IS_F32>
__device__ __forceinline__ float ldx(const void* p, size_t i) {
    if (IS_F32) {
        return ((const float*)p)[i];
    } else {
        unsigned short u = ((const unsigned short*)p)[i];
        return __uint_as_float(((unsigned)u) << 16);
    }
}

__device__ __forceinline__ float bfbits2f(unsigned short u) {
    return __uint_as_float(((unsigned)u) << 16);
}

__device__ __forceinline__ unsigned short f2bfbits(float v) {
    __hip_bfloat16 b = __float2bfloat16(v);
    unsigned short us; __builtin_memcpy(&us, &b, 2);
    return us;
}

// ---------------------------------------------------------------------------
// Dtype detector (proven): flag=1 if f32 dataset, 0 if bf16.
// ---------------------------------------------------------------------------
__global__ __launch_bounds__(1024) void k_detect(
    const float* __restrict__ norm_f, int* __restrict__ flag)
{
    __shared__ int sbad;
    if (threadIdx.x == 0) sbad = 0;
    __syncthreads();
    float v = norm_f[threadIdx.x];
    int bad = (v != v || fabsf(v) > 1e3f) ? 1 : 0;
    if (bad) atomicOr(&sbad, 1);
    __syncthreads();
    if (threadIdx.x == 0) *flag = sbad ? 0 : 1;
}

// ---------------------------------------------------------------------------
// Bucket histogram (proven structure; bucket = dst>>5 now).
// ---------------------------------------------------------------------------
__global__ __launch_bounds__(256) void k_bhist(
    const int* __restrict__ dst, int* __restrict__ H)
{
    __shared__ int hist[NBKT];
    for (int i = threadIdx.x; i < NBKT; i += 256) hist[i] = 0;
    __syncthreads();
    const int e0 = blockIdx.x * P1_CHUNK;
    for (int i = threadIdx.x; i < P1_CHUNK; i += 256) {
        int e = e0 + i;
        if (e < N_EDGES) atomicAdd(&hist[dst[e] >> BKT_SH], 1);
    }
    __syncthreads();
    for (int b = threadIdx.x; b < NBKT; b += 256)
        H[blockIdx.x * NBKT + b] = hist[b];
}

__global__ __launch_bounds__(256) void k_bscan1(
    const int* __restrict__ H, int* __restrict__ OT, int* __restrict__ tot)
{
    __shared__ int col[P1_GRID];
    const int b = blockIdx.x;
    for (int i = threadIdx.x; i < P1_GRID; i += 256)
        col[i] = H[i * NBKT + b];
    __syncthreads();
    if (threadIdx.x < 64) {
        const int lane = threadIdx.x;
        int carry = 0;
        for (int chunk = 0; chunk < (P1_GRID + 63) / 64; ++chunk) {
            int i = chunk * 64 + lane;
            int c = (i < P1_GRID) ? col[i] : 0;
            int incl = c;
#pragma unroll
            for (int off = 1; off < 64; off <<= 1) {
                int t = __shfl_up(incl, off, 64);
                if (lane >= off) incl += t;
            }
            if (i < P1_GRID) col[i] = carry + incl - c;
            carry += __shfl(incl, 63, 64);
        }
        if (lane == 0) tot[b] = carry;
    }
    __syncthreads();
    for (int i = threadIdx.x; i < P1_GRID; i += 256)
        OT[(size_t)b * P1_GRID + i] = col[i];
}

__global__ __launch_bounds__(64) void k_bscan2(
    const int* __restrict__ tot, int* __restrict__ base)
{
    const int lane = threadIdx.x;
    int carry = 0;
    for (int chunk = 0; chunk < (NBKT + 63) / 64; ++chunk) {
        int i = chunk * 64 + lane;
        int c = (i < NBKT) ? tot[i] : 0;
        int incl = c;
#pragma unroll
        for (int off = 1; off < 64; off <<= 1) {
            int t = __shfl_up(incl, off, 64);
            if (lane >= off) incl += t;
        }
        if (i < NBKT) base[i] = carry + incl - c;
        carry += __shfl(incl, 63, 64);
    }
    if (lane == 0) base[NBKT] = carry;   // == N_EDGES
}

// ---------------------------------------------------------------------------
// P1 (proven): multisplit into bucket runs, deterministic reservation.
// rec: [7:0]=dst&31, [23:8]=src, [27:24]=rel, [47:32]=norm bf16.
// ---------------------------------------------------------------------------
template<int IS_F32>
__device__ __forceinline__ void p1_body(
    const int* __restrict__ src, const int* __restrict__ dst,
    const int* __restrict__ rel, const void* __restrict__ norm_raw,
    const int* __restrict__ base, const int* __restrict__ OT,
    unsigned long long* __restrict__ R, int* curs)
{
    const int blk = blockIdx.x;
    for (int b = threadIdx.x; b < NBKT; b += 256)
        curs[b] = base[b] + OT[(size_t)b * P1_GRID + blk];
    __syncthreads();
    const int e0 = blk * P1_CHUNK;
    for (int i = threadIdx.x; i < P1_CHUNK; i += 256) {
        int e = e0 + i;
        if (e >= N_EDGES) continue;
        int d = dst[e];
        int pos = atomicAdd(&curs[d >> BKT_SH], 1);
        unsigned short nb = f2bfbits(ldx<IS_F32>(norm_raw, e));
        unsigned long long rec =
              (unsigned long long)(d & (BKT_SZ - 1))
            | ((unsigned long long)(unsigned)src[e] << 8)
            | ((unsigned long long)(unsigned)rel[e] << 24)
            | ((unsigned long long)nb << 32);
        R[pos] = rec;
    }
}

__global__ __launch_bounds__(256) void k_p1(
    const int* __restrict__ src, const int* __restrict__ dst,
    const int* __restrict__ rel, const void* __restrict__ norm_raw,
    const int* __restrict__ base, const int* __restrict__ OT,
    unsigned long long* __restrict__ R, const int* __restrict__ flag)
{
    __shared__ int curs[NBKT];
    if (*flag) p1_body<1>(src, dst, rel, norm_raw, base, OT, R, curs);
    else       p1_body<0>(src, dst, rel, norm_raw, base, OT, R, curs);
}

// ---------------------------------------------------------------------------
// P2SEG: per bucket, split run into 16 rel segments, each padded to x16.
// packed2: [7:0]=dstlocal, [23:8]=src. Pad entries are all-zero (norm=0).
// Segment starts are 16-aligned (gbase = align16(base[b]) + b*SEG_PAD).
// ---------------------------------------------------------------------------
__global__ __launch_bounds__(256) void k_p2seg(
    const int* __restrict__ base,
    const unsigned long long* __restrict__ R,
    unsigned* __restrict__ packed2,
    unsigned short* __restrict__ normS,
    int* __restrict__ segBase,
    int* __restrict__ segCnt)
{
    __shared__ int cnt[16], curs[16], sbl[16];
    const int tid = threadIdx.x;
    if (tid < 16) { cnt[tid] = 0; curs[tid] = 0; }
    __syncthreads();

    const int b  = blockIdx.x;
    const int c0 = base[b], c1 = base[b + 1];

    for (int i = c0 + tid; i < c1; i += 256)
        atomicAdd(&cnt[(int)((R[i] >> 24) & 15)], 1);
    __syncthreads();

    if (tid == 0) {
        int g = ((c0 + 15) & ~15) + b * SEG_PAD;
        for (int r = 0; r < 16; ++r) {
            sbl[r] = g;
            g += (cnt[r] + 15) & ~15;
        }
    }
    __syncthreads();
    if (tid < 16) {
        segBase[b * 16 + tid] = sbl[tid];
        segCnt[b * 16 + tid]  = cnt[tid];
    }

    for (int i = c0 + tid; i < c1; i += 256) {
        unsigned long long rec = R[i];
        int r = (int)((rec >> 24) & 15);
        int pos = sbl[r] + atomicAdd(&curs[r], 1);
        packed2[pos] = (unsigned)(rec & 0xFFFFFFu);
        normS[pos]   = (unsigned short)(rec >> 32);
    }
    __syncthreads();

    {   // pads: <=15 per segment, 16 segments -> 256 candidate slots
        int r = tid >> 4, j = tid & 15;
        int c = cnt[r], p = (c + 15) & ~15;
        if (j < p - c) {
            int pos = sbl[r] + c + j;
            packed2[pos] = 0;
            normS[pos]   = 0;
        }
    }
}

// ---------------------------------------------------------------------------
// PREP: h -> bf16 copy (6.4 MB, the L2-resident gather target) and
// W -> pre-swizzled bf16 B-fragment layout (k1's proven swizzle, stride 40).
// ---------------------------------------------------------------------------
__global__ __launch_bounds__(256) void k_prep(
    const void* __restrict__ h_raw, const void* __restrict__ w_raw,
    unsigned short* __restrict__ hbf, unsigned short* __restrict__ Wswz,
    const int* __restrict__ flag)
{
    const int f = *flag;
    const int blk = blockIdx.x;
    if (blk < PREP_HBLK) {
        int i0 = blk * 1024 + threadIdx.x * 4;
        if (f) {
            float4 v = *(const float4*)((const float*)h_raw + i0);
            ushort4v o;
            o[0] = f2bfbits(v.x); o[1] = f2bfbits(v.y);
            o[2] = f2bfbits(v.z); o[3] = f2bfbits(v.w);
            *(ushort4v*)(hbf + i0) = o;
        } else {
            *(uint2*)(hbf + i0) = *(const uint2*)((const unsigned short*)h_raw + i0);
        }
    } else {
        int rel = blk - PREP_HBLK;
        for (int idx = threadIdx.x; idx < 4096; idx += 256) {
            int d = idx >> 6, o = idx & 63;
            float wv = f ? ((const float*)w_raw)[(size_t)((rel << 6) + d) * 64 + o]
                         : bfbits2f(((const unsigned short*)w_raw)[(size_t)((rel << 6) + d) * 64 + o]);
            int c = d >> 5, q = (d >> 3) & 3, j = d & 7;
            Wswz[(size_t)rel * 5120 + ((c << 6) + o) * 40 + q * 8 + j] = f2bfbits(wv);
        }
    }
}

// ---------------------------------------------------------------------------
// K_FUSED: per 32-dst bucket. Waves own disjoint rel segments (no barriers
// in main loop). W[rel] B-frags reg-resident per segment; gather 16 h rows
// per group (16 B/lane from 6.4 MB L2-resident hbf); 8 MFMA; norm-scale;
// ds_add_f32 scatter into LDS accumulator (stride 66 -> ~2-way banks).
// ---------------------------------------------------------------------------
__global__ __launch_bounds__(256, 4) void k_fused(
    const unsigned* __restrict__ packed2,
    const unsigned short* __restrict__ normS,
    const unsigned short* __restrict__ hbf,
    const unsigned short* __restrict__ Wswz,
    const int* __restrict__ segBase,
    const int* __restrict__ segCnt,
    void* __restrict__ out, const int* __restrict__ flag)
{
    __shared__ float outacc[BKT_SZ * 66];
    const int tid  = threadIdx.x;
    const int lane = tid & 63, wave = tid >> 6;
    const int n15  = lane & 15, quad = lane >> 4;
    const int b    = blockIdx.x;

    for (int i = tid; i < BKT_SZ * 66; i += 256) outacc[i] = 0.f;
    __syncthreads();

    for (int r = wave; r < 16; r += 4) {
        const int sb  = segBase[b * 16 + r];
        const int cnt = segCnt[b * 16 + r];
        if (cnt == 0) continue;
        const int ng = (cnt + 15) >> 4;

        // B fragments for this rel, register-resident for the whole segment.
        short8 bf0[4], bf1[4];
        const unsigned short* wp = Wswz + (size_t)r * 5120;
#pragma unroll
        for (int t = 0; t < 4; ++t) {
            uint4 v0 = *(const uint4*)(wp + (t * 16 + n15) * 40 + quad * 8);
            uint4 v1 = *(const uint4*)(wp + (64 + t * 16 + n15) * 40 + quad * 8);
            __builtin_memcpy(&bf0[t], &v0, 16);
            __builtin_memcpy(&bf1[t], &v1, 16);
        }

        for (int g = 0; g < ng; ++g) {
            const int e0 = sb + g * 16;
            unsigned ps = packed2[e0 + n15];          // src for A row n15
            int srow = (int)(ps >> 8);
            uint4 pm = *(const uint4*)(packed2 + e0 + quad * 4);
            ushort4v nm = *(const ushort4v*)(normS + e0 + quad * 4);

            const uint4* ap = (const uint4*)(hbf + (size_t)srow * 64);
            uint4 av0 = ap[quad];        // K 0..31 slice for this quad
            uint4 av1 = ap[quad + 4];    // K 32..63
            short8 a0, a1;
            __builtin_memcpy(&a0, &av0, 16);
            __builtin_memcpy(&a1, &av1, 16);

            float4v acc[4];
#pragma unroll
            for (int t = 0; t < 4; ++t) acc[t] = (float4v){0.f, 0.f, 0.f, 0.f};
#pragma unroll
            for (int t = 0; t < 4; ++t)
                acc[t] = __builtin_amdgcn_mfma_f32_16x16x32_bf16(a0, bf0[t], acc[t], 0, 0, 0);
#pragma unroll
            for (int t = 0; t < 4; ++t)
                acc[t] = __builtin_amdgcn_mfma_f32_16x16x32_bf16(a1, bf1[t], acc[t], 0, 0, 0);

            float nf0 = bfbits2f(nm[0]), nf1 = bfbits2f(nm[1]);
            float nf2 = bfbits2f(nm[2]), nf3 = bfbits2f(nm[3]);
            int d0 = pm.x & (BKT_SZ - 1), d1 = pm.y & (BKT_SZ - 1);
            int d2 = pm.z & (BKT_SZ - 1), d3 = pm.w & (BKT_SZ - 1);

#pragma unroll
            for (int t = 0; t < 4; ++t) {
                int col = t * 16 + n15;
                atomicAdd(&outacc[d0 * 66 + col], acc[t][0] * nf0);
                atomicAdd(&outacc[d1 * 66 + col], acc[t][1] * nf1);
                atomicAdd(&outacc[d2 * 66 + col], acc[t][2] * nf2);
                atomicAdd(&outacc[d3 * 66 + col], acc[t][3] * nf3);
            }
        }
    }
    __syncthreads();

    const int v0n = b << BKT_SH;
    const int nn  = min(BKT_SZ, N_NODES - v0n);
    const int f   = *flag;
    for (int idx = tid; idx < nn * 64; idx += 256) {
        int row = idx >> 6, col = idx & 63;
        float rv = fmaxf(outacc[row * 66 + col], 0.f);
        size_t ob = (size_t)(v0n + row) * 64 + col;
        if (f) ((float*)out)[ob] = rv;
        else   ((unsigned short*)out)[ob] = f2bfbits(rv);
    }
}

// ---------------------------------------------------------------------------
extern "C" void kernel_launch(void* const* d_in, const int* in_sizes, int n_in,
                              void* d_out, int out_size, void* d_ws, size_t ws_size,
                              hipStream_t stream)
{
    const void* h      = d_in[0];
    const void* weight = d_in[1];
    const void* norm   = d_in[2];
    const int* src = (const int*)d_in[3];
    const int* dst = (const int*)d_in[4];
    const int* rel = (const int*)d_in[5];

    char* w = (char*)d_ws;
    int* flag = (int*)w;                        w += 256;
    int* base = (int*)w;                        w += ((NBKT + 1) * 4 + 255) / 256 * 256;
    int* tot  = (int*)w;                        w += (NBKT * 4 + 255) / 256 * 256;
    int* H    = (int*)w;                        w += ((size_t)P1_GRID * NBKT * 4 + 255) / 256 * 256;
    int* OT   = (int*)w;                        w += ((size_t)NBKT * P1_GRID * 4 + 255) / 256 * 256;
    int* segBase = (int*)w;                     w += (NBKT * 16 * 4 + 255) / 256 * 256;
    int* segCnt  = (int*)w;                     w += (NBKT * 16 * 4 + 255) / 256 * 256;
    unsigned long long* R = (unsigned long long*)w;  w += (size_t)N_EDGES * 8;
    unsigned* packed2 = (unsigned*)w;           w += (size_t)EMAX * 4;
    unsigned short* normS = (unsigned short*)w; w += (size_t)EMAX * 2;
    unsigned short* hbf = (unsigned short*)w;   w += (size_t)N_NODES * DIM * 2;
    unsigned short* Wswz = (unsigned short*)w;  w += (size_t)NREL * 5120 * 2;

    k_detect<<<1, 1024, 0, stream>>>((const float*)norm, flag);

    k_bhist<<<P1_GRID, 256, 0, stream>>>(dst, H);
    k_bscan1<<<NBKT, 256, 0, stream>>>(H, OT, tot);
    k_bscan2<<<1, 64, 0, stream>>>(tot, base);

    k_p1<<<P1_GRID, 256, 0, stream>>>(src, dst, rel, norm, base, OT, R, flag);
    k_p2seg<<<NBKT, 256, 0, stream>>>(base, R, packed2, normS, segBase, segCnt);

    k_prep<<<PREP_HBLK + NREL, 256, 0, stream>>>(h, weight, hbf, Wswz, flag);

    k_fused<<<NBKT, 256, 0, stream>>>(packed2, normS, hbf, Wswz,
                                      segBase, segCnt, d_out, flag);
}